// Round 3
// baseline (155.210 us; speedup 1.0000x reference)
//
#include <hip/hip_runtime.h>
#include <hip/hip_cooperative_groups.h>

#define BATCH 8192
#define FEAT  512
#define FUSED_BLOCKS 1024   // 4 waves/block -> 4096 waves -> 2 rows/wave

namespace cg = cooperative_groups;

__global__ __launch_bounds__(256) void center_loss_fused(
    const float* __restrict__ features,
    const int*   __restrict__ labels,
    const float* __restrict__ centers,
    float*       __restrict__ partials,
    float*       __restrict__ out)
{
    const int lane  = threadIdx.x & 63;
    const int wave  = threadIdx.x >> 6;
    const int gwave = blockIdx.x * 4 + wave;      // 0..4095
    const int row0  = gwave * 2;
    const int row1  = row0 + 1;

    // wave-uniform label loads first; everything below overlaps their latency
    const int l0 = labels[row0];
    const int l1 = labels[row1];
    const float4* f0 = reinterpret_cast<const float4*>(features + (size_t)row0 * FEAT);
    const float4* f1 = reinterpret_cast<const float4*>(features + (size_t)row1 * FEAT);
    const float4* c0 = reinterpret_cast<const float4*>(centers  + (size_t)l0  * FEAT);
    const float4* c1 = reinterpret_cast<const float4*>(centers  + (size_t)l1  * FEAT);

    // 8 outstanding 1KB coalesced loads per wave (deep MLP)
    float4 a0 = f0[lane];
    float4 a1 = f0[lane + 64];
    float4 a2 = f1[lane];
    float4 a3 = f1[lane + 64];
    float4 b0 = c0[lane];
    float4 b1 = c0[lane + 64];
    float4 b2 = c1[lane];
    float4 b3 = c1[lane + 64];

    float acc, d;
    d = a0.x - b0.x; acc  = d * d;
    d = a0.y - b0.y; acc += d * d;
    d = a0.z - b0.z; acc += d * d;
    d = a0.w - b0.w; acc += d * d;
    d = a1.x - b1.x; acc += d * d;
    d = a1.y - b1.y; acc += d * d;
    d = a1.z - b1.z; acc += d * d;
    d = a1.w - b1.w; acc += d * d;
    d = a2.x - b2.x; acc += d * d;
    d = a2.y - b2.y; acc += d * d;
    d = a2.z - b2.z; acc += d * d;
    d = a2.w - b2.w; acc += d * d;
    d = a3.x - b3.x; acc += d * d;
    d = a3.y - b3.y; acc += d * d;
    d = a3.z - b3.z; acc += d * d;
    d = a3.w - b3.w; acc += d * d;

    #pragma unroll
    for (int off = 32; off > 0; off >>= 1)
        acc += __shfl_down(acc, off, 64);

    if (lane == 0) partials[gwave] = acc;
    __threadfence();
    cg::this_grid().sync();

    if (blockIdx.x == 0) {
        // 4096 floats = 1024 float4; 256 threads x 4 float4 each
        const float4* p = reinterpret_cast<const float4*>(partials);
        float4 q0 = p[threadIdx.x];
        float4 q1 = p[threadIdx.x + 256];
        float4 q2 = p[threadIdx.x + 512];
        float4 q3 = p[threadIdx.x + 768];
        float s = (q0.x + q0.y + q0.z + q0.w) + (q1.x + q1.y + q1.z + q1.w)
                + (q2.x + q2.y + q2.z + q2.w) + (q3.x + q3.y + q3.z + q3.w);
        #pragma unroll
        for (int off = 32; off > 0; off >>= 1)
            s += __shfl_down(s, off, 64);
        __shared__ float smem[4];
        if (lane == 0) smem[wave] = s;
        __syncthreads();
        if (threadIdx.x == 0)
            out[0] = (smem[0] + smem[1] + smem[2] + smem[3]) * (1.0f / BATCH);
    }
}

// ---------------- fallback 2-kernel path (proven in R2) ----------------

__global__ __launch_bounds__(256) void center_loss_partial(
    const float* __restrict__ features,
    const int*   __restrict__ labels,
    const float* __restrict__ centers,
    float*       __restrict__ partials)
{
    const int lane = threadIdx.x & 63;
    const int wave = threadIdx.x >> 6;
    const int row  = blockIdx.x * 4 + wave;

    const int lbl = labels[row];
    const float4* f = reinterpret_cast<const float4*>(features + (size_t)row * FEAT);
    const float4* c = reinterpret_cast<const float4*>(centers  + (size_t)lbl * FEAT);

    float4 f0 = f[lane];
    float4 f1 = f[lane + 64];
    float4 c0 = c[lane];
    float4 c1 = c[lane + 64];

    float acc, d;
    d = f0.x - c0.x; acc  = d * d;
    d = f0.y - c0.y; acc += d * d;
    d = f0.z - c0.z; acc += d * d;
    d = f0.w - c0.w; acc += d * d;
    d = f1.x - c1.x; acc += d * d;
    d = f1.y - c1.y; acc += d * d;
    d = f1.z - c1.z; acc += d * d;
    d = f1.w - c1.w; acc += d * d;

    #pragma unroll
    for (int off = 32; off > 0; off >>= 1)
        acc += __shfl_down(acc, off, 64);

    __shared__ float smem[4];
    if (lane == 0) smem[wave] = acc;
    __syncthreads();
    if (threadIdx.x == 0)
        partials[blockIdx.x] = smem[0] + smem[1] + smem[2] + smem[3];
}

__global__ __launch_bounds__(256) void center_loss_reduce(
    const float* __restrict__ partials,
    float*       __restrict__ out)
{
    const float4* p = reinterpret_cast<const float4*>(partials);
    float4 a = p[threadIdx.x];
    float4 b = p[threadIdx.x + 256];
    float s = (a.x + a.y + a.z + a.w) + (b.x + b.y + b.z + b.w);

    #pragma unroll
    for (int off = 32; off > 0; off >>= 1)
        s += __shfl_down(s, off, 64);

    __shared__ float smem[4];
    const int lane = threadIdx.x & 63;
    const int wave = threadIdx.x >> 6;
    if (lane == 0) smem[wave] = s;
    __syncthreads();
    if (threadIdx.x == 0)
        out[0] = (smem[0] + smem[1] + smem[2] + smem[3]) * (1.0f / BATCH);
}

extern "C" void kernel_launch(void* const* d_in, const int* in_sizes, int n_in,
                              void* d_out, int out_size, void* d_ws, size_t ws_size,
                              hipStream_t stream) {
    const float* features = (const float*)d_in[0];
    const int*   labels   = (const int*)d_in[1];
    const float* centers  = (const float*)d_in[2];
    float* out      = (float*)d_out;
    float* partials = (float*)d_ws;   // 4096 floats, written unconditionally each call

    void* kargs[] = { (void*)&features, (void*)&labels, (void*)&centers,
                      (void*)&partials, (void*)&out };
    hipError_t e = hipLaunchCooperativeKernel((const void*)center_loss_fused,
                                              dim3(FUSED_BLOCKS), dim3(256),
                                              kargs, 0, stream);
    if (e != hipSuccess) {
        // cooperative launch unavailable (e.g., under capture) -> 2-dispatch path
        center_loss_partial<<<BATCH / 4, 256, 0, stream>>>(features, labels, centers, partials);
        center_loss_reduce<<<1, 256, 0, stream>>>(partials, out);
    }
}

// Round 4
// 55.338 us; speedup vs baseline: 2.8048x; 2.8048x over previous
//
#include <hip/hip_runtime.h>

#define BATCH 8192
#define FEAT  512
#define NBLK  (BATCH / 4)   // 2048 blocks, 4 waves/block, one wave per row

__global__ __launch_bounds__(256) void center_loss_onepass(
    const float* __restrict__ features,
    const int*   __restrict__ labels,
    const float* __restrict__ centers,
    float*       __restrict__ partials,   // d_ws: NBLK floats
    unsigned*    __restrict__ ticket,     // d_ws + NBLK: 1 uint (self-maintaining)
    float*       __restrict__ out)
{
    const int lane = threadIdx.x & 63;
    const int wave = threadIdx.x >> 6;
    const int row  = blockIdx.x * 4 + wave;

    // wave-uniform label first; feature loads overlap its latency
    const int lbl = labels[row];
    const float4* f = reinterpret_cast<const float4*>(features + (size_t)row * FEAT);
    const float4* c = reinterpret_cast<const float4*>(centers  + (size_t)lbl * FEAT);

    // 512 floats = 128 float4; 64 lanes -> 2 float4 each, 1 KB coalesced per load
    float4 f0 = f[lane];
    float4 f1 = f[lane + 64];
    float4 c0 = c[lane];
    float4 c1 = c[lane + 64];

    float acc, d;
    d = f0.x - c0.x; acc  = d * d;
    d = f0.y - c0.y; acc += d * d;
    d = f0.z - c0.z; acc += d * d;
    d = f0.w - c0.w; acc += d * d;
    d = f1.x - c1.x; acc += d * d;
    d = f1.y - c1.y; acc += d * d;
    d = f1.z - c1.z; acc += d * d;
    d = f1.w - c1.w; acc += d * d;

    #pragma unroll
    for (int off = 32; off > 0; off >>= 1)
        acc += __shfl_down(acc, off, 64);

    __shared__ float smem[4];
    __shared__ int   s_winner;
    if (lane == 0) smem[wave] = acc;
    __syncthreads();

    if (threadIdx.x == 0) {
        partials[blockIdx.x] = smem[0] + smem[1] + smem[2] + smem[3];
        __threadfence();  // release: partial visible device-wide before ticket
        // atomicInc cycles 0..NBLK-1; from ANY start (0xAA poison or leftover
        // NBLK-1) exactly the LAST arrival sees old == NBLK-2, and the counter
        // always ends the call at NBLK-1 -> deterministic across replays.
        unsigned old = atomicInc(ticket, NBLK - 1);
        s_winner = (old == NBLK - 2);
    }
    __syncthreads();

    if (s_winner) {
        __threadfence();  // acquire: see all other blocks' partials
        // 2048 floats = 512 float4; 256 threads x 2 float4 each
        const float4* p = reinterpret_cast<const float4*>(partials);
        float4 a = p[threadIdx.x];
        float4 b = p[threadIdx.x + 256];
        float s = (a.x + a.y + a.z + a.w) + (b.x + b.y + b.z + b.w);
        #pragma unroll
        for (int off = 32; off > 0; off >>= 1)
            s += __shfl_down(s, off, 64);
        __shared__ float smem2[4];
        if (lane == 0) smem2[wave] = s;
        __syncthreads();
        if (threadIdx.x == 0)
            out[0] = (smem2[0] + smem2[1] + smem2[2] + smem2[3]) * (1.0f / BATCH);
    }
}

extern "C" void kernel_launch(void* const* d_in, const int* in_sizes, int n_in,
                              void* d_out, int out_size, void* d_ws, size_t ws_size,
                              hipStream_t stream) {
    const float* features = (const float*)d_in[0];
    const int*   labels   = (const int*)d_in[1];
    const float* centers  = (const float*)d_in[2];
    float*    out      = (float*)d_out;
    float*    partials = (float*)d_ws;                 // NBLK floats
    unsigned* ticket   = (unsigned*)(partials + NBLK); // 1 uint, self-maintaining

    center_loss_onepass<<<NBLK, 256, 0, stream>>>(features, labels, centers,
                                                  partials, ticket, out);
}

// Round 5
// 31.724 us; speedup vs baseline: 4.8925x; 1.7444x over previous
//
#include <hip/hip_runtime.h>

#define BATCH 8192
#define FEAT  512
#define NBLK  (BATCH / 4)   // 2048 blocks, 4 waves/block, one wave per row

__global__ __launch_bounds__(256) void center_loss_onepass(
    const float* __restrict__ features,
    const int*   __restrict__ labels,
    const float* __restrict__ centers,
    float*       __restrict__ partials,   // d_ws: NBLK floats
    unsigned*    __restrict__ ticket,     // d_ws + NBLK: 1 uint (self-maintaining)
    float*       __restrict__ out)
{
    const int lane = threadIdx.x & 63;
    const int wave = threadIdx.x >> 6;
    const int row  = blockIdx.x * 4 + wave;

    // wave-uniform label first; feature loads overlap its latency
    const int lbl = labels[row];
    const float4* f = reinterpret_cast<const float4*>(features + (size_t)row * FEAT);
    const float4* c = reinterpret_cast<const float4*>(centers  + (size_t)lbl * FEAT);

    // 512 floats = 128 float4; 64 lanes -> 2 float4 each, 1 KB coalesced per load
    float4 f0 = f[lane];
    float4 f1 = f[lane + 64];
    float4 c0 = c[lane];
    float4 c1 = c[lane + 64];

    float acc, d;
    d = f0.x - c0.x; acc  = d * d;
    d = f0.y - c0.y; acc += d * d;
    d = f0.z - c0.z; acc += d * d;
    d = f0.w - c0.w; acc += d * d;
    d = f1.x - c1.x; acc += d * d;
    d = f1.y - c1.y; acc += d * d;
    d = f1.z - c1.z; acc += d * d;
    d = f1.w - c1.w; acc += d * d;

    #pragma unroll
    for (int off = 32; off > 0; off >>= 1)
        acc += __shfl_down(acc, off, 64);

    __shared__ float smem[4];
    __shared__ int   s_winner;
    if (lane == 0) smem[wave] = acc;
    __syncthreads();

    if (threadIdx.x == 0) {
        // Device-coherent (sc1, write-through) store: lands at the coherent
        // point directly, so NO buffer_wbl2 / L2 writeback fence is needed.
        __hip_atomic_store(&partials[blockIdx.x],
                           smem[0] + smem[1] + smem[2] + smem[3],
                           __ATOMIC_RELAXED, __HIP_MEMORY_SCOPE_AGENT);
        // Order: partial store acked at coherent point BEFORE the ticket RMW.
        // Manual vmcnt drain only -- no C++ fence, no cache maintenance ops.
        asm volatile("s_waitcnt vmcnt(0)" ::: "memory");
        // atomicInc cycles 0..NBLK-1; from ANY start (0xAA poison or leftover
        // NBLK-1) exactly the LAST arrival sees old == NBLK-2, and the counter
        // ends every call at NBLK-1 -> deterministic across graph replays.
        unsigned old = atomicInc(ticket, NBLK - 1);
        s_winner = (old == NBLK - 2);
    }
    __syncthreads();

    if (s_winner) {
        // All other blocks' incs precede ours at the coherent point, and each
        // inc was preceded by that block's coherent partial store. Agent-scope
        // (sc1) loads bypass our stale L1/L2 -- no buffer_inv needed.
        const int t = threadIdx.x;
        float s = 0.0f;
        #pragma unroll
        for (int k = 0; k < NBLK / 256; ++k)
            s += __hip_atomic_load(&partials[t + k * 256],
                                   __ATOMIC_RELAXED, __HIP_MEMORY_SCOPE_AGENT);
        #pragma unroll
        for (int off = 32; off > 0; off >>= 1)
            s += __shfl_down(s, off, 64);
        __shared__ float smem2[4];
        if (lane == 0) smem2[wave] = s;
        __syncthreads();
        if (threadIdx.x == 0)
            out[0] = (smem2[0] + smem2[1] + smem2[2] + smem2[3]) * (1.0f / BATCH);
    }
}

extern "C" void kernel_launch(void* const* d_in, const int* in_sizes, int n_in,
                              void* d_out, int out_size, void* d_ws, size_t ws_size,
                              hipStream_t stream) {
    const float* features = (const float*)d_in[0];
    const int*   labels   = (const int*)d_in[1];
    const float* centers  = (const float*)d_in[2];
    float*    out      = (float*)d_out;
    float*    partials = (float*)d_ws;                 // NBLK floats
    unsigned* ticket   = (unsigned*)(partials + NBLK); // 1 uint, self-maintaining

    center_loss_onepass<<<NBLK, 256, 0, stream>>>(features, labels, centers,
                                                  partials, ticket, out);
}

// Round 6
// 12.962 us; speedup vs baseline: 11.9746x; 2.4475x over previous
//
#include <hip/hip_runtime.h>

#define BATCH 8192
#define FEAT  512
#define NBLK  256                 // 1 block/CU; ONLY 256 ticket atomics (R5 had 2048 -> ~25us serialization)
#define NTHR  1024                // 16 waves/block
#define ROWS_PER_WAVE 2           // 8192 rows / (256 blk * 16 waves) = 2

__global__ __launch_bounds__(NTHR) void center_loss_onepass(
    const float* __restrict__ features,
    const int*   __restrict__ labels,
    const float* __restrict__ centers,
    float*       __restrict__ partials,   // d_ws: NBLK floats
    unsigned*    __restrict__ ticket,     // d_ws + NBLK: 1 uint (self-maintaining)
    float*       __restrict__ out)
{
    const int lane  = threadIdx.x & 63;
    const int wave  = threadIdx.x >> 6;                  // 0..15
    const int gwave = blockIdx.x * 16 + wave;            // 0..4095
    const int row0  = gwave * ROWS_PER_WAVE;
    const int row1  = row0 + 1;

    // wave-uniform labels first; all 8 vector loads below overlap their latency
    const int l0 = labels[row0];
    const int l1 = labels[row1];
    const float4* f0 = reinterpret_cast<const float4*>(features + (size_t)row0 * FEAT);
    const float4* f1 = reinterpret_cast<const float4*>(features + (size_t)row1 * FEAT);
    const float4* c0 = reinterpret_cast<const float4*>(centers  + (size_t)l0  * FEAT);
    const float4* c1 = reinterpret_cast<const float4*>(centers  + (size_t)l1  * FEAT);

    // 8 outstanding 1KB coalesced loads per wave
    float4 a0 = f0[lane];
    float4 a1 = f0[lane + 64];
    float4 a2 = f1[lane];
    float4 a3 = f1[lane + 64];
    float4 b0 = c0[lane];
    float4 b1 = c0[lane + 64];
    float4 b2 = c1[lane];
    float4 b3 = c1[lane + 64];

    float acc, d;
    d = a0.x - b0.x; acc  = d * d;
    d = a0.y - b0.y; acc += d * d;
    d = a0.z - b0.z; acc += d * d;
    d = a0.w - b0.w; acc += d * d;
    d = a1.x - b1.x; acc += d * d;
    d = a1.y - b1.y; acc += d * d;
    d = a1.z - b1.z; acc += d * d;
    d = a1.w - b1.w; acc += d * d;
    d = a2.x - b2.x; acc += d * d;
    d = a2.y - b2.y; acc += d * d;
    d = a2.z - b2.z; acc += d * d;
    d = a2.w - b2.w; acc += d * d;
    d = a3.x - b3.x; acc += d * d;
    d = a3.y - b3.y; acc += d * d;
    d = a3.z - b3.z; acc += d * d;
    d = a3.w - b3.w; acc += d * d;

    #pragma unroll
    for (int off = 32; off > 0; off >>= 1)
        acc += __shfl_down(acc, off, 64);

    __shared__ float smem[16];
    __shared__ int   s_winner;
    if (lane == 0) smem[wave] = acc;
    __syncthreads();

    if (threadIdx.x == 0) {
        float p = 0.0f;
        #pragma unroll
        for (int w = 0; w < 16; ++w) p += smem[w];
        // Device-coherent (sc1, write-through) store: lands at the coherent
        // point directly -- no buffer_wbl2 / L2 writeback needed (R5-proven).
        __hip_atomic_store(&partials[blockIdx.x], p,
                           __ATOMIC_RELAXED, __HIP_MEMORY_SCOPE_AGENT);
        // Order: partial store acked at coherent point BEFORE the ticket RMW.
        asm volatile("s_waitcnt vmcnt(0)" ::: "memory");
        // atomicInc cycles 0..NBLK-1; from ANY start (0xAA poison or leftover
        // NBLK-1) exactly the LAST arrival sees old == NBLK-2, and the counter
        // ends every call at NBLK-1 -> deterministic across graph replays.
        unsigned old = atomicInc(ticket, NBLK - 1);
        s_winner = (old == NBLK - 2);
    }
    __syncthreads();

    if (s_winner && wave == 0) {
        // Last block: all 255 other incs (each preceded by that block's
        // coherent partial store) are ordered before ours. sc1 loads bypass
        // stale local L1/L2. 256 floats, one wave: 4 loads/lane + shuffle.
        float s = __hip_atomic_load(&partials[lane],
                                    __ATOMIC_RELAXED, __HIP_MEMORY_SCOPE_AGENT)
                + __hip_atomic_load(&partials[lane + 64],
                                    __ATOMIC_RELAXED, __HIP_MEMORY_SCOPE_AGENT)
                + __hip_atomic_load(&partials[lane + 128],
                                    __ATOMIC_RELAXED, __HIP_MEMORY_SCOPE_AGENT)
                + __hip_atomic_load(&partials[lane + 192],
                                    __ATOMIC_RELAXED, __HIP_MEMORY_SCOPE_AGENT);
        #pragma unroll
        for (int off = 32; off > 0; off >>= 1)
            s += __shfl_down(s, off, 64);
        if (lane == 0)
            out[0] = s * (1.0f / BATCH);
    }
}

extern "C" void kernel_launch(void* const* d_in, const int* in_sizes, int n_in,
                              void* d_out, int out_size, void* d_ws, size_t ws_size,
                              hipStream_t stream) {
    const float* features = (const float*)d_in[0];
    const int*   labels   = (const int*)d_in[1];
    const float* centers  = (const float*)d_in[2];
    float*    out      = (float*)d_out;
    float*    partials = (float*)d_ws;                 // NBLK floats
    unsigned* ticket   = (unsigned*)(partials + NBLK); // 1 uint, self-maintaining

    center_loss_onepass<<<NBLK, NTHR, 0, stream>>>(features, labels, centers,
                                                   partials, ticket, out);
}

// Round 7
// 11.926 us; speedup vs baseline: 13.0145x; 1.0868x over previous
//
#include <hip/hip_runtime.h>

#define BATCH 8192
#define FEAT  512
#define NBLK  2048                 // full-occupancy geometry (R2-proven): 8 blk/CU
#define NCTR  32                   // ticket shards; 64 arrivals each ~0.8us, parallel
#define GRP   (NBLK / NCTR)        // 64 blocks per shard
#define CTR_STRIDE 16              // 16 uints = 64B -> one cache line per counter

__global__ __launch_bounds__(256) void center_loss_onepass(
    const float* __restrict__ features,
    const int*   __restrict__ labels,
    const float* __restrict__ centers,
    float*       __restrict__ partials,   // d_ws: NBLK floats
    unsigned*    __restrict__ ctr1,       // NCTR counters, 64B apart, self-maintaining
    unsigned*    __restrict__ ctr2,       // 1 counter, self-maintaining
    float*       __restrict__ out)
{
    const int lane = threadIdx.x & 63;
    const int wave = threadIdx.x >> 6;
    const int row  = blockIdx.x * 4 + wave;   // one row per wave

    // wave-uniform label first; feature loads overlap its latency
    const int lbl = labels[row];
    const float4* f = reinterpret_cast<const float4*>(features + (size_t)row * FEAT);
    const float4* c = reinterpret_cast<const float4*>(centers  + (size_t)lbl * FEAT);

    float4 f0 = f[lane];
    float4 f1 = f[lane + 64];
    float4 c0 = c[lane];
    float4 c1 = c[lane + 64];

    float acc, d;
    d = f0.x - c0.x; acc  = d * d;
    d = f0.y - c0.y; acc += d * d;
    d = f0.z - c0.z; acc += d * d;
    d = f0.w - c0.w; acc += d * d;
    d = f1.x - c1.x; acc += d * d;
    d = f1.y - c1.y; acc += d * d;
    d = f1.z - c1.z; acc += d * d;
    d = f1.w - c1.w; acc += d * d;

    #pragma unroll
    for (int off = 32; off > 0; off >>= 1)
        acc += __shfl_down(acc, off, 64);

    __shared__ float smem[4];
    __shared__ int   s_winner;
    if (lane == 0) smem[wave] = acc;
    __syncthreads();

    if (threadIdx.x == 0) {
        // sc1 write-through store: lands at device-coherent point, no wbl2 (R5/R6-proven)
        __hip_atomic_store(&partials[blockIdx.x],
                           smem[0] + smem[1] + smem[2] + smem[3],
                           __ATOMIC_RELAXED, __HIP_MEMORY_SCOPE_AGENT);
        // order: partial store acked at coherent point BEFORE the ticket RMW
        asm volatile("s_waitcnt vmcnt(0)" ::: "memory");
        // Sharded ticket. atomicInc(p, N-1) cycles 0..N-1 from ANY start
        // (0xAA poison or leftover N-1); exactly the last arrival per call
        // sees old == N-2, and the counter ends every call at N-1.
        const int g = blockIdx.x & (NCTR - 1);       // 64 blocks per shard
        unsigned o1 = atomicInc(&ctr1[g * CTR_STRIDE], GRP - 1);
        int win = 0;
        if (o1 == GRP - 2) {                          // last in shard (64th)
            // ctr1 observation orders this shard's 64 partial stores globally;
            // ctr2 observation chain orders ALL shards before the global winner.
            unsigned o2 = atomicInc(ctr2, NCTR - 1);
            win = (o2 == NCTR - 2);                   // last shard (32nd)
        }
        s_winner = win;
    }
    __syncthreads();

    if (s_winner) {
        // Global winner: every other block's partial store is ordered before
        // our ctr2 observation. sc1 loads bypass stale local L1/L2.
        const int t = threadIdx.x;
        float s = 0.0f;
        #pragma unroll
        for (int k = 0; k < NBLK / 256; ++k)          // 8 loads/thread
            s += __hip_atomic_load(&partials[t + k * 256],
                                   __ATOMIC_RELAXED, __HIP_MEMORY_SCOPE_AGENT);
        #pragma unroll
        for (int off = 32; off > 0; off >>= 1)
            s += __shfl_down(s, off, 64);
        __shared__ float smem2[4];
        if (lane == 0) smem2[wave] = s;
        __syncthreads();
        if (threadIdx.x == 0)
            out[0] = (smem2[0] + smem2[1] + smem2[2] + smem2[3]) * (1.0f / BATCH);
    }
}

extern "C" void kernel_launch(void* const* d_in, const int* in_sizes, int n_in,
                              void* d_out, int out_size, void* d_ws, size_t ws_size,
                              hipStream_t stream) {
    const float* features = (const float*)d_in[0];
    const int*   labels   = (const int*)d_in[1];
    const float* centers  = (const float*)d_in[2];
    float*    out      = (float*)d_out;
    float*    partials = (float*)d_ws;                         // NBLK floats
    unsigned* ctr1     = (unsigned*)(partials + NBLK);         // NCTR x 64B
    unsigned* ctr2     = ctr1 + NCTR * CTR_STRIDE;             // 1 uint

    center_loss_onepass<<<NBLK, 256, 0, stream>>>(features, labels, centers,
                                                  partials, ctr1, ctr2, out);
}